// Round 1
// baseline (449.408 us; speedup 1.0000x reference)
//
#include <hip/hip_runtime.h>

typedef _Float16 f16x8 __attribute__((ext_vector_type(8)));
typedef _Float16 f16x4 __attribute__((ext_vector_type(4)));
typedef float    f32x4 __attribute__((ext_vector_type(4)));

static __device__ __forceinline__ f32x4 mfma16(f16x8 a, f16x8 b, f32x4 c) {
    return __builtin_amdgcn_mfma_f32_16x16x32_f16(a, b, c, 0, 0, 0);
}

// async global->LDS, 16B per lane; LDS dest is wave-uniform base + lane*16
static __device__ __forceinline__ void gload_lds16(const _Float16* g, _Float16* lds) {
    __builtin_amdgcn_global_load_lds(
        (const __attribute__((address_space(1))) unsigned int*)g,
        (__attribute__((address_space(3))) unsigned int*)lds, 16, 0, 0);
}

// ---------------------------------------------------------------------------
// Kernel 1: Bayesian weight sampling (fp16 out) + KL partial sums
// ---------------------------------------------------------------------------
__global__ __launch_bounds__(256) void k_sample(
    const float* __restrict__ qm, const float* __restrict__ km, const float* __restrict__ vm,
    const float* __restrict__ qs, const float* __restrict__ ks, const float* __restrict__ vs,
    const float* __restrict__ om, const float* __restrict__ os,
    const float* __restrict__ eq, const float* __restrict__ ek,
    const float* __restrict__ ev, const float* __restrict__ eo,
    _Float16* __restrict__ wq, _Float16* __restrict__ wk,
    _Float16* __restrict__ wv, _Float16* __restrict__ wo,
    float* __restrict__ part)
{
    int i = blockIdx.x * 256 + threadIdx.x;
    float aqm = qm[i], akm = km[i], avm = vm[i];
    float aqs = qs[i], aks = ks[i], avs = vs[i];
    float aom = om[i], aos = os[i];
    wq[i] = (_Float16)(aqm + eq[i] * __expf(aqs));
    wk[i] = (_Float16)(akm + ek[i] * __expf(aks));
    wv[i] = (_Float16)(avm + ev[i] * __expf(avs));
    // faithful bug: output weight built from value_mean + eps_o*exp(output_std)
    wo[i] = (_Float16)(avm + eo[i] * __expf(aos));
    float t = aqm*aqm - 2.f*aqs + __expf(2.f*aqs)
            + akm*akm - 2.f*aks + __expf(2.f*aks)
            + avm*avm - 2.f*avs + __expf(2.f*avs)
            + aom*aom - 2.f*aos + __expf(2.f*aos);
    #pragma unroll
    for (int m = 1; m < 64; m <<= 1) t += __shfl_xor(t, m, 64);
    __shared__ float red[4];
    int w = threadIdx.x >> 6, lane = threadIdx.x & 63;
    if (lane == 0) red[w] = t;
    __syncthreads();
    if (threadIdx.x == 0) part[blockIdx.x] = red[0] + red[1] + red[2] + red[3];
}

// ---------------------------------------------------------------------------
// Kernel 2: fp32 -> fp16 convert (dec_inp)
// ---------------------------------------------------------------------------
__global__ __launch_bounds__(256) void k_cvt(const float* __restrict__ in,
                                             _Float16* __restrict__ outh)
{
    int i = (blockIdx.x * 256 + threadIdx.x) * 4;
    float4 v = *(const float4*)&in[i];
    f16x4 hv;
    hv[0] = (_Float16)v.x; hv[1] = (_Float16)v.y;
    hv[2] = (_Float16)v.z; hv[3] = (_Float16)v.w;
    *(f16x4*)&outh[i] = hv;
}

// ---------------------------------------------------------------------------
// Kernel 3/5: C = A(M,K) * B(N,K)^T, 128x128 tile, BK=64, m97 structure.
// mode 0: C fp16   mode 1: xout = resid + C (fp32)
// blockIdx.z selects weight/output slice (QKV fusion).
// ---------------------------------------------------------------------------
__global__ __launch_bounds__(256) void k_gemm(
    const _Float16* __restrict__ A, const _Float16* __restrict__ B0,
    _Float16* __restrict__ C0, const float* __restrict__ resid,
    float* __restrict__ xout, int mode)
{
    __shared__ __align__(16) _Float16 As[128 * 64];
    __shared__ __align__(16) _Float16 Bs[128 * 64];
    const int K = 1024, N = 1024;
    const _Float16* Bp = B0 + (size_t)blockIdx.z * 1048576u;
    _Float16* Cp = C0 + (size_t)blockIdx.z * 8388608u;
    int tN = blockIdx.x * 128, tM = blockIdx.y * 128;
    int tid = threadIdx.x, w = tid >> 6, lane = tid & 63;
    int wm = w & 1, wn = w >> 1;
    int q = lane >> 4, r = lane & 15;
    f32x4 acc[4][4] = {};
    for (int kk = 0; kk < K; kk += 64) {
        __syncthreads();            // prior ds_reads drained before restaging
        #pragma unroll
        for (int i = 0; i < 4; ++i) {
            int chunk = w * 4 + i;                 // 16 x 1KB chunks per matrix
            int row = chunk * 8 + (lane >> 3);     // 0..127
            int ko = (lane & 7) * 8;               // fp16 offset within BK
            gload_lds16(A  + (size_t)(tM + row) * K + kk + ko, &As[chunk * 512]);
            gload_lds16(Bp + (size_t)(tN + row) * K + kk + ko, &Bs[chunk * 512]);
        }
        __syncthreads();            // vmcnt(0) drain lands the LDS data
        #pragma unroll
        for (int kc = 0; kc < 2; ++kc) {
            f16x8 af[4], bf[4];
            #pragma unroll
            for (int m = 0; m < 4; ++m)
                af[m] = *(const f16x8*)&As[(wm*64 + m*16 + r)*64 + kc*32 + q*8];
            #pragma unroll
            for (int n = 0; n < 4; ++n)
                bf[n] = *(const f16x8*)&Bs[(wn*64 + n*16 + r)*64 + kc*32 + q*8];
            #pragma unroll
            for (int m = 0; m < 4; ++m)
                #pragma unroll
                for (int n = 0; n < 4; ++n)
                    acc[m][n] = mfma16(af[m], bf[n], acc[m][n]);
        }
    }
    // epilogue: C/D layout row = q*4+t, col = r  (verified m89/m91)
    #pragma unroll
    for (int m = 0; m < 4; ++m)
      #pragma unroll
      for (int n = 0; n < 4; ++n)
        #pragma unroll
        for (int t = 0; t < 4; ++t) {
            int row = tM + wm*64 + m*16 + q*4 + t;
            int col = tN + wn*64 + n*16 + r;
            size_t o = (size_t)row * N + col;
            if (mode == 0) Cp[o] = (_Float16)acc[m][n][t];
            else           xout[o] = resid[o] + acc[m][n][t];
        }
}

// ---------------------------------------------------------------------------
// Kernel 4: causal flash attention per (q-tile=128, batch, head)
// ---------------------------------------------------------------------------
__global__ __launch_bounds__(256) void k_attn(
    const _Float16* __restrict__ Qb, const _Float16* __restrict__ Kb,
    const _Float16* __restrict__ Vb, _Float16* __restrict__ AVo)
{
    __shared__ __align__(16) _Float16 Ks[64 * 72];    // K-tile row-major (+8 pad)
    __shared__ __align__(16) _Float16 Vt[64 * 72];    // V-tile transposed (d, j)
    __shared__ __align__(16) _Float16 Ps[4 * 32 * 72];// per-wave P (i, j)
    int qt = blockIdx.x, b = blockIdx.y, h = blockIdx.z;
    int tid = threadIdx.x, w = tid >> 6, lane = tid & 63;
    int q = lane >> 4, r = lane & 15;
    int wbase = qt * 128 + w * 32;                    // this wave's 32 q-rows
    f16x8 qf[2][2];
    #pragma unroll
    for (int it = 0; it < 2; ++it)
      #pragma unroll
      for (int kc = 0; kc < 2; ++kc) {
          int s = wbase + it * 16 + r;
          qf[it][kc] = *(const f16x8*)&Qb[((size_t)s*8 + b)*1024 + h*64 + kc*32 + q*8];
      }
    f32x4 o[2][4] = {};
    float mrun[2][4], lrun[2][4];
    #pragma unroll
    for (int it = 0; it < 2; ++it)
      #pragma unroll
      for (int t = 0; t < 4; ++t) { mrun[it][t] = -1e30f; lrun[it][t] = 0.f; }
    _Float16* Pw = &Ps[w * 2304];
    int nkt = (qt + 1) * 2;                           // causal: tiles 0..(qt*128+127)/64
    for (int kt = 0; kt < nkt; ++kt) {
        __syncthreads();
        #pragma unroll
        for (int rep = 0; rep < 2; ++rep) {           // stage K row-major, V transposed
            int lin = tid + rep * 256;
            int j = lin >> 3, c = lin & 7;
            size_t gofs = (((size_t)(kt*64 + j))*8 + b)*1024 + h*64 + c*8;
            f16x8 kv = *(const f16x8*)&Kb[gofs];
            *(f16x8*)&Ks[j*72 + c*8] = kv;
            f16x8 vv = *(const f16x8*)&Vb[gofs];
            #pragma unroll
            for (int e = 0; e < 8; ++e) Vt[(c*8 + e)*72 + j] = vv[e];
        }
        __syncthreads();
        f32x4 sa[2][4] = {};
        #pragma unroll
        for (int kc = 0; kc < 2; ++kc) {
            f16x8 kf[4];
            #pragma unroll
            for (int jt = 0; jt < 4; ++jt)
                kf[jt] = *(const f16x8*)&Ks[(jt*16 + r)*72 + kc*32 + q*8];
            #pragma unroll
            for (int it = 0; it < 2; ++it)
              #pragma unroll
              for (int jt = 0; jt < 4; ++jt)
                sa[it][jt] = mfma16(qf[it][kc], kf[jt], sa[it][jt]);
        }
        #pragma unroll
        for (int it = 0; it < 2; ++it) {
          #pragma unroll
          for (int t = 0; t < 4; ++t) {
            int qrow = wbase + it*16 + q*4 + t;
            float sv[4]; float mx = -1e30f;
            #pragma unroll
            for (int jt = 0; jt < 4; ++jt) {
                int kcol = kt*64 + jt*16 + r;
                float x = sa[it][jt][t] * 0.125f;     // 1/sqrt(64)
                if (kcol > qrow) x = -1e30f;          // causal triu(k=1) mask
                sv[jt] = x; mx = fmaxf(mx, x);
            }
            mx = fmaxf(mx, __shfl_xor(mx, 1));
            mx = fmaxf(mx, __shfl_xor(mx, 2));
            mx = fmaxf(mx, __shfl_xor(mx, 4));
            mx = fmaxf(mx, __shfl_xor(mx, 8));
            float mnew = fmaxf(mrun[it][t], mx);
            float al = __expf(mrun[it][t] - mnew);
            mrun[it][t] = mnew;
            float ps = 0.f;
            #pragma unroll
            for (int jt = 0; jt < 4; ++jt) {
                float p = __expf(sv[jt] - mnew);
                ps += p;
                Pw[(it*16 + q*4 + t)*72 + jt*16 + r] = (_Float16)p;
            }
            ps += __shfl_xor(ps, 1);
            ps += __shfl_xor(ps, 2);
            ps += __shfl_xor(ps, 4);
            ps += __shfl_xor(ps, 8);
            lrun[it][t] = lrun[it][t] * al + ps;
            #pragma unroll
            for (int dt = 0; dt < 4; ++dt) o[it][dt][t] *= al;
          }
        }
        #pragma unroll
        for (int kc = 0; kc < 2; ++kc) {              // O += P @ V
            f16x8 pf[2], vf[4];
            #pragma unroll
            for (int it = 0; it < 2; ++it)
                pf[it] = *(const f16x8*)&Pw[(it*16 + r)*72 + kc*32 + q*8];
            #pragma unroll
            for (int dt = 0; dt < 4; ++dt)
                vf[dt] = *(const f16x8*)&Vt[(dt*16 + r)*72 + kc*32 + q*8];
            #pragma unroll
            for (int it = 0; it < 2; ++it)
              #pragma unroll
              for (int dt = 0; dt < 4; ++dt)
                o[it][dt] = mfma16(pf[it], vf[dt], o[it][dt]);
        }
    }
    #pragma unroll
    for (int it = 0; it < 2; ++it)
      #pragma unroll
      for (int t = 0; t < 4; ++t) {
        int s = wbase + it*16 + q*4 + t;
        float inv = 1.f / lrun[it][t];
        #pragma unroll
        for (int dt = 0; dt < 4; ++dt)
            AVo[((size_t)s*8 + b)*1024 + h*64 + dt*16 + r] = (_Float16)(o[it][dt][t] * inv);
      }
}

// ---------------------------------------------------------------------------
// Kernel 6: in-place LayerNorm on d_out rows (1024 wide)
// ---------------------------------------------------------------------------
__global__ __launch_bounds__(256) void k_ln(float* __restrict__ x,
    const float* __restrict__ g, const float* __restrict__ bta)
{
    int row = blockIdx.x;
    float* xr = x + (size_t)row * 1024;
    int t4 = threadIdx.x * 4;
    float4 v = *(const float4*)&xr[t4];
    float s  = v.x + v.y + v.z + v.w;
    float s2 = v.x*v.x + v.y*v.y + v.z*v.z + v.w*v.w;
    #pragma unroll
    for (int m = 1; m < 64; m <<= 1) { s += __shfl_xor(s, m, 64); s2 += __shfl_xor(s2, m, 64); }
    __shared__ float rs[4], rs2[4];
    int w = threadIdx.x >> 6, lane = threadIdx.x & 63;
    if (lane == 0) { rs[w] = s; rs2[w] = s2; }
    __syncthreads();
    s  = rs[0] + rs[1] + rs[2] + rs[3];
    s2 = rs2[0] + rs2[1] + rs2[2] + rs2[3];
    float mu = s * (1.f / 1024.f);
    float var = s2 * (1.f / 1024.f) - mu * mu;
    float rstd = rsqrtf(var + 1e-5f);
    float4 gv = *(const float4*)&g[t4];
    float4 bv = *(const float4*)&bta[t4];
    float4 ov;
    ov.x = (v.x - mu) * rstd * gv.x + bv.x;
    ov.y = (v.y - mu) * rstd * gv.y + bv.y;
    ov.z = (v.z - mu) * rstd * gv.z + bv.z;
    ov.w = (v.w - mu) * rstd * gv.w + bv.w;
    *(float4*)&xr[t4] = ov;
}

// ---------------------------------------------------------------------------
// Kernel 7: KL finalize
// ---------------------------------------------------------------------------
__global__ __launch_bounds__(256) void k_klfin(const float* __restrict__ part,
                                               float* __restrict__ out)
{
    float s = 0.f;
    for (int i = threadIdx.x; i < 4096; i += 256) s += part[i];
    #pragma unroll
    for (int m = 1; m < 64; m <<= 1) s += __shfl_xor(s, m, 64);
    __shared__ float red[4];
    int w = threadIdx.x >> 6, lane = threadIdx.x & 63;
    if (lane == 0) red[w] = s;
    __syncthreads();
    if (threadIdx.x == 0)
        out[8388608] = (red[0] + red[1] + red[2] + red[3]) * (0.5f / 4194304.f);
}

// ---------------------------------------------------------------------------
extern "C" void kernel_launch(void* const* d_in, const int* in_sizes, int n_in,
                              void* d_out, int out_size, void* d_ws, size_t ws_size,
                              hipStream_t stream)
{
    (void)in_sizes; (void)n_in; (void)out_size; (void)ws_size;
    const float* dec   = (const float*)d_in[0];
    // d_in[1] = attn_mask: statically causal (j > i), not read
    const float* qm    = (const float*)d_in[2];
    const float* km    = (const float*)d_in[3];
    const float* vm    = (const float*)d_in[4];
    const float* qs    = (const float*)d_in[5];
    const float* ks    = (const float*)d_in[6];
    const float* vs    = (const float*)d_in[7];
    const float* om    = (const float*)d_in[8];
    const float* os    = (const float*)d_in[9];
    const float* gamma = (const float*)d_in[10];
    const float* beta  = (const float*)d_in[11];
    const float* eq    = (const float*)d_in[12];
    const float* ek    = (const float*)d_in[13];
    const float* ev    = (const float*)d_in[14];
    const float* eo    = (const float*)d_in[15];

    char* ws = (char*)d_ws;
    _Float16* WQ   = (_Float16*)ws;                       // 4 x 1M fp16 = 8 MB
    float*    PART = (float*)(ws + (8ull  << 20));        // 16 KB
    _Float16* XH   = (_Float16*)(ws + (9ull  << 20));     // 16 MB
    _Float16* Qh   = (_Float16*)(ws + (25ull << 20));     // Q,K,V contiguous 48 MB
    _Float16* AV   = XH;                                  // reuse: XH dead after QKV GEMM
    float*    out  = (float*)d_out;                       // x fp32 lives in d_out

    k_sample<<<dim3(4096), dim3(256), 0, stream>>>(
        qm, km, vm, qs, ks, vs, om, os, eq, ek, ev, eo,
        WQ, WQ + 1048576, WQ + 2097152, WQ + 3145728, PART);
    k_cvt<<<dim3(8192), dim3(256), 0, stream>>>(dec, XH);
    k_gemm<<<dim3(8, 64, 3), dim3(256), 0, stream>>>(XH, WQ, Qh, dec, out, 0);
    k_attn<<<dim3(8, 8, 16), dim3(256), 0, stream>>>(Qh, Qh + 8388608, Qh + 16777216, AV);
    k_gemm<<<dim3(8, 64, 1), dim3(256), 0, stream>>>(AV, WQ + 3145728, Qh, dec, out, 1);
    k_ln<<<dim3(8192), dim3(256), 0, stream>>>(out, gamma, beta);
    k_klfin<<<dim3(1), dim3(256), 0, stream>>>(PART, out);
}

// Round 2
// 366.669 us; speedup vs baseline: 1.2257x; 1.2257x over previous
//
#include <hip/hip_runtime.h>

typedef _Float16 f16x8 __attribute__((ext_vector_type(8)));
typedef _Float16 f16x4 __attribute__((ext_vector_type(4)));
typedef float    f32x4 __attribute__((ext_vector_type(4)));

static __device__ __forceinline__ f32x4 mfma16(f16x8 a, f16x8 b, f32x4 c) {
    return __builtin_amdgcn_mfma_f32_16x16x32_f16(a, b, c, 0, 0, 0);
}

// async global->LDS, 16B per lane; LDS dest is wave-uniform base + lane*16
static __device__ __forceinline__ void gload_lds16(const _Float16* g, _Float16* lds) {
    __builtin_amdgcn_global_load_lds(
        (const __attribute__((address_space(1))) unsigned int*)g,
        (__attribute__((address_space(3))) unsigned int*)lds, 16, 0, 0);
}

// ---------------------------------------------------------------------------
// Kernel 1: Bayesian weight sampling (fp16 out) + KL partial sums
// ---------------------------------------------------------------------------
__global__ __launch_bounds__(256) void k_sample(
    const float* __restrict__ qm, const float* __restrict__ km, const float* __restrict__ vm,
    const float* __restrict__ qs, const float* __restrict__ ks, const float* __restrict__ vs,
    const float* __restrict__ om, const float* __restrict__ os,
    const float* __restrict__ eq, const float* __restrict__ ek,
    const float* __restrict__ ev, const float* __restrict__ eo,
    _Float16* __restrict__ wq, _Float16* __restrict__ wk,
    _Float16* __restrict__ wv, _Float16* __restrict__ wo,
    float* __restrict__ part)
{
    int i = blockIdx.x * 256 + threadIdx.x;
    float aqm = qm[i], akm = km[i], avm = vm[i];
    float aqs = qs[i], aks = ks[i], avs = vs[i];
    float aom = om[i], aos = os[i];
    wq[i] = (_Float16)(aqm + eq[i] * __expf(aqs));
    wk[i] = (_Float16)(akm + ek[i] * __expf(aks));
    wv[i] = (_Float16)(avm + ev[i] * __expf(avs));
    // faithful bug: output weight built from value_mean + eps_o*exp(output_std)
    wo[i] = (_Float16)(avm + eo[i] * __expf(aos));
    float t = aqm*aqm - 2.f*aqs + __expf(2.f*aqs)
            + akm*akm - 2.f*aks + __expf(2.f*aks)
            + avm*avm - 2.f*avs + __expf(2.f*avs)
            + aom*aom - 2.f*aos + __expf(2.f*aos);
    #pragma unroll
    for (int m = 1; m < 64; m <<= 1) t += __shfl_xor(t, m, 64);
    __shared__ float red[4];
    int w = threadIdx.x >> 6, lane = threadIdx.x & 63;
    if (lane == 0) red[w] = t;
    __syncthreads();
    if (threadIdx.x == 0) part[blockIdx.x] = red[0] + red[1] + red[2] + red[3];
}

// ---------------------------------------------------------------------------
// Kernel 2: fp32 -> fp16 convert (dec_inp)
// ---------------------------------------------------------------------------
__global__ __launch_bounds__(256) void k_cvt(const float* __restrict__ in,
                                             _Float16* __restrict__ outh)
{
    int i = (blockIdx.x * 256 + threadIdx.x) * 4;
    float4 v = *(const float4*)&in[i];
    f16x4 hv;
    hv[0] = (_Float16)v.x; hv[1] = (_Float16)v.y;
    hv[2] = (_Float16)v.z; hv[3] = (_Float16)v.w;
    *(f16x4*)&outh[i] = hv;
}

// ---------------------------------------------------------------------------
// Kernel 3/6: C = A(M,K) * B(N,K)^T, 128x128 tile, BK=64, m97 structure.
// mode 0: C fp16 (z==0 slice pre-scaled by 1/sqrt(Dh) for attention)
// mode 1: xout = resid + C (fp32)
// blockIdx.z selects weight/output slice (QKV fusion).
// ---------------------------------------------------------------------------
__global__ __launch_bounds__(256) void k_gemm(
    const _Float16* __restrict__ A, const _Float16* __restrict__ B0,
    _Float16* __restrict__ C0, const float* __restrict__ resid,
    float* __restrict__ xout, int mode)
{
    __shared__ __align__(16) _Float16 As[128 * 64];
    __shared__ __align__(16) _Float16 Bs[128 * 64];
    const int K = 1024, N = 1024;
    const _Float16* Bp = B0 + (size_t)blockIdx.z * 1048576u;
    _Float16* Cp = C0 + (size_t)blockIdx.z * 8388608u;
    int tN = blockIdx.x * 128, tM = blockIdx.y * 128;
    int tid = threadIdx.x, w = tid >> 6, lane = tid & 63;
    int wm = w & 1, wn = w >> 1;
    int q = lane >> 4, r = lane & 15;
    f32x4 acc[4][4] = {};
    for (int kk = 0; kk < K; kk += 64) {
        __syncthreads();            // prior ds_reads drained before restaging
        #pragma unroll
        for (int i = 0; i < 4; ++i) {
            int chunk = w * 4 + i;                 // 16 x 1KB chunks per matrix
            int row = chunk * 8 + (lane >> 3);     // 0..127
            int ko = (lane & 7) * 8;               // fp16 offset within BK
            gload_lds16(A  + (size_t)(tM + row) * K + kk + ko, &As[chunk * 512]);
            gload_lds16(Bp + (size_t)(tN + row) * K + kk + ko, &Bs[chunk * 512]);
        }
        __syncthreads();            // vmcnt(0) drain lands the LDS data
        #pragma unroll
        for (int kc = 0; kc < 2; ++kc) {
            f16x8 af[4], bf[4];
            #pragma unroll
            for (int m = 0; m < 4; ++m)
                af[m] = *(const f16x8*)&As[(wm*64 + m*16 + r)*64 + kc*32 + q*8];
            #pragma unroll
            for (int n = 0; n < 4; ++n)
                bf[n] = *(const f16x8*)&Bs[(wn*64 + n*16 + r)*64 + kc*32 + q*8];
            #pragma unroll
            for (int m = 0; m < 4; ++m)
                #pragma unroll
                for (int n = 0; n < 4; ++n)
                    acc[m][n] = mfma16(af[m], bf[n], acc[m][n]);
        }
    }
    // softmax scale folded into Q (z==0) so attention hot loop has no scaling
    float sc = (mode == 0 && blockIdx.z == 0) ? 0.125f : 1.0f;
    // epilogue: C/D layout row = q*4+t, col = r  (verified m89/m91)
    #pragma unroll
    for (int m = 0; m < 4; ++m)
      #pragma unroll
      for (int n = 0; n < 4; ++n)
        #pragma unroll
        for (int t = 0; t < 4; ++t) {
            int row = tM + wm*64 + m*16 + q*4 + t;
            int col = tN + wn*64 + n*16 + r;
            size_t o = (size_t)row * N + col;
            if (mode == 0) Cp[o] = (_Float16)(acc[m][n][t] * sc);
            else           xout[o] = resid[o] + acc[m][n][t];
        }
}

// ---------------------------------------------------------------------------
// Kernel 4: transpose V once: [s][b][h*64+d] -> Vt[(b*16+h)*64+d][s]
// ---------------------------------------------------------------------------
__global__ __launch_bounds__(256) void k_vtrans(const _Float16* __restrict__ V,
                                                _Float16* __restrict__ Vt)
{
    __shared__ __align__(16) _Float16 L[64 * 72];
    int c = blockIdx.x;                 // b*16+h
    int b = c >> 4, h = c & 15;
    int s0 = blockIdx.y * 64;
    int tid = threadIdx.x;
    #pragma unroll
    for (int rep = 0; rep < 2; ++rep) {
        int idx = rep * 256 + tid;
        int sl = idx >> 3, ch = idx & 7;
        f16x8 v = *(const f16x8*)&V[((size_t)(s0 + sl) * 8 + b) * 1024 + h * 64 + ch * 8];
        *(f16x8*)&L[sl * 72 + ch * 8] = v;
    }
    __syncthreads();
    #pragma unroll
    for (int rep = 0; rep < 2; ++rep) {
        int idx = rep * 256 + tid;
        int d = idx >> 3, c2 = idx & 7;   // c2 fast -> coalesced 128B/8 lanes out
        f16x8 o;
        #pragma unroll
        for (int e = 0; e < 8; ++e) o[e] = L[(c2 * 8 + e) * 72 + d];
        *(f16x8*)&Vt[((size_t)c * 64 + d) * 1024 + s0 + c2 * 8] = o;
    }
}

// ---------------------------------------------------------------------------
// Kernel 5: causal flash attention, S^T formulation.
//   S^T = K·Q^T  -> lane holds j in registers (16/lane), i = lane r
//   softmax over j: in-register tree + 2 shuffles (xor 16/32)
//   O^T = V^T·P^T via mfma(A=V^T frag, B=P frag); P via vectorized LDS
// grid (bh=128, qt=8): consecutive blocks share qt -> per-CU qt mix balanced
// ---------------------------------------------------------------------------
__global__ __launch_bounds__(256, 4) void k_attn(
    const _Float16* __restrict__ Qb, const _Float16* __restrict__ Kb,
    const _Float16* __restrict__ Vtg, _Float16* __restrict__ AVo)
{
    __shared__ __align__(16) _Float16 Ks[64 * 64];   // rows j, cols d (gload, no pad)
    __shared__ __align__(16) _Float16 Vs[64 * 64];   // rows d, cols j (gload, no pad)
    __shared__ __align__(16) _Float16 Ps[4 * 32 * 72]; // per-wave P[i][j], pad 72
    const int bh = blockIdx.x;            // 0..127
    const int b = bh & 7, h = bh >> 3;
    const int cbh = b * 16 + h;           // Vt row-group index
    const int qt = blockIdx.y;            // 0..7
    const int tid = threadIdx.x, w = tid >> 6, lane = tid & 63;
    const int q = lane >> 4, r = lane & 15;
    const int i0 = qt * 128 + w * 32;     // this wave's i-base

    f16x8 qf[2][2];                       // Q B-fragments (pre-scaled by 0.125)
    #pragma unroll
    for (int it = 0; it < 2; ++it)
      #pragma unroll
      for (int kc = 0; kc < 2; ++kc)
        qf[it][kc] = *(const f16x8*)&Qb[((size_t)(i0 + it*16 + r)*8 + b)*1024 + h*64 + kc*32 + q*8];

    f32x4 ot[4][2] = {};                  // O^T acc: [dtb][it], d=dtb*16+q*4+t, i=it*16+r
    float mrun[2] = {-1e30f, -1e30f}, lrun[2] = {0.f, 0.f};
    _Float16* Pw = &Ps[w * 2304];

    auto tile = [&](int kt, bool MASK) __attribute__((always_inline)) {
        __syncthreads();                  // prior tile's LDS reads drained
        #pragma unroll
        for (int ii = 0; ii < 2; ++ii) {  // stage K-tile + Vt-tile, 8KB each
            int chunk = w * 2 + ii;
            int row = chunk * 8 + (lane >> 3);
            int co = (lane & 7) * 8;
            gload_lds16(Kb  + ((size_t)(kt*64 + row)*8 + b)*1024 + h*64 + co, &Ks[chunk*512]);
            gload_lds16(Vtg + ((size_t)(cbh*64 + row))*1024 + kt*64 + co,     &Vs[chunk*512]);
        }
        __syncthreads();                  // vmcnt(0) drain lands the tiles

        f32x4 st[4][2] = {};              // S^T: [jt][it], j=jt*16+q*4+t, i=it*16+r
        #pragma unroll
        for (int kc = 0; kc < 2; ++kc) {
            f16x8 kf[4];
            #pragma unroll
            for (int jt = 0; jt < 4; ++jt)
                kf[jt] = *(const f16x8*)&Ks[(jt*16 + r)*64 + kc*32 + q*8];
            #pragma unroll
            for (int jt = 0; jt < 4; ++jt)
              #pragma unroll
              for (int it = 0; it < 2; ++it)
                st[jt][it] = mfma16(kf[jt], qf[it][kc], st[jt][it]);
        }

        #pragma unroll
        for (int it = 0; it < 2; ++it) {
            if (MASK) {
                int il = i0 + it*16 + r;
                #pragma unroll
                for (int jt = 0; jt < 4; ++jt)
                  #pragma unroll
                  for (int t = 0; t < 4; ++t)
                    if (kt*64 + jt*16 + q*4 + t > il) st[jt][it][t] = -1e30f;
            }
            float mx = -1e30f;            // in-register max over 16 j values
            #pragma unroll
            for (int jt = 0; jt < 4; ++jt) {
                f32x4 s4 = st[jt][it];
                mx = fmaxf(mx, fmaxf(fmaxf(s4[0], s4[1]), fmaxf(s4[2], s4[3])));
            }
            mx = fmaxf(mx, __shfl_xor(mx, 16, 64));
            mx = fmaxf(mx, __shfl_xor(mx, 32, 64));
            float mnew = fmaxf(mrun[it], mx);
            float al = __expf(mrun[it] - mnew);
            mrun[it] = mnew;
            float ps = 0.f;
            #pragma unroll
            for (int jt = 0; jt < 4; ++jt) {   // exp + pack + vector LDS write
                f16x4 hv;
                #pragma unroll
                for (int t = 0; t < 4; ++t) {
                    float e = __expf(st[jt][it][t] - mnew);
                    ps += e;
                    hv[t] = (_Float16)e;
                }
                *(f16x4*)&Pw[(it*16 + r)*72 + jt*16 + q*4] = hv;
            }
            ps += __shfl_xor(ps, 16, 64);
            ps += __shfl_xor(ps, 32, 64);
            lrun[it] = lrun[it] * al + ps;
            #pragma unroll
            for (int dtb = 0; dtb < 4; ++dtb) ot[dtb][it] *= al;
        }

        #pragma unroll
        for (int kc = 0; kc < 2; ++kc) {  // O^T += V^T-frag x P-frag
            f16x8 vf[4], pf[2];
            #pragma unroll
            for (int dtb = 0; dtb < 4; ++dtb)
                vf[dtb] = *(const f16x8*)&Vs[(dtb*16 + r)*64 + kc*32 + q*8];
            #pragma unroll
            for (int it = 0; it < 2; ++it)
                pf[it] = *(const f16x8*)&Pw[(it*16 + r)*72 + kc*32 + q*8];
            #pragma unroll
            for (int dtb = 0; dtb < 4; ++dtb)
              #pragma unroll
              for (int it = 0; it < 2; ++it)
                ot[dtb][it] = mfma16(vf[dtb], pf[it], ot[dtb][it]);
        }
    };

    for (int kt = 0; kt < 2*qt; ++kt) tile(kt, false);  // interior: no mask
    tile(2*qt,     true);                               // diagonal tiles
    tile(2*qt + 1, true);

    #pragma unroll
    for (int it = 0; it < 2; ++it) {
        float inv = 1.f / lrun[it];
        int s = i0 + it*16 + r;
        #pragma unroll
        for (int dtb = 0; dtb < 4; ++dtb) {
            f16x4 hv;
            #pragma unroll
            for (int t = 0; t < 4; ++t) hv[t] = (_Float16)(ot[dtb][it][t] * inv);
            *(f16x4*)&AVo[((size_t)s*8 + b)*1024 + h*64 + dtb*16 + q*4] = hv;
        }
    }
}

// ---------------------------------------------------------------------------
// Kernel 7: in-place LayerNorm on d_out rows (1024 wide)
// ---------------------------------------------------------------------------
__global__ __launch_bounds__(256) void k_ln(float* __restrict__ x,
    const float* __restrict__ g, const float* __restrict__ bta)
{
    int row = blockIdx.x;
    float* xr = x + (size_t)row * 1024;
    int t4 = threadIdx.x * 4;
    float4 v = *(const float4*)&xr[t4];
    float s  = v.x + v.y + v.z + v.w;
    float s2 = v.x*v.x + v.y*v.y + v.z*v.z + v.w*v.w;
    #pragma unroll
    for (int m = 1; m < 64; m <<= 1) { s += __shfl_xor(s, m, 64); s2 += __shfl_xor(s2, m, 64); }
    __shared__ float rs[4], rs2[4];
    int w = threadIdx.x >> 6, lane = threadIdx.x & 63;
    if (lane == 0) { rs[w] = s; rs2[w] = s2; }
    __syncthreads();
    s  = rs[0] + rs[1] + rs[2] + rs[3];
    s2 = rs2[0] + rs2[1] + rs2[2] + rs2[3];
    float mu = s * (1.f / 1024.f);
    float var = s2 * (1.f / 1024.f) - mu * mu;
    float rstd = rsqrtf(var + 1e-5f);
    float4 gv = *(const float4*)&g[t4];
    float4 bv = *(const float4*)&bta[t4];
    float4 ov;
    ov.x = (v.x - mu) * rstd * gv.x + bv.x;
    ov.y = (v.y - mu) * rstd * gv.y + bv.y;
    ov.z = (v.z - mu) * rstd * gv.z + bv.z;
    ov.w = (v.w - mu) * rstd * gv.w + bv.w;
    *(float4*)&xr[t4] = ov;
}

// ---------------------------------------------------------------------------
// Kernel 8: KL finalize
// ---------------------------------------------------------------------------
__global__ __launch_bounds__(256) void k_klfin(const float* __restrict__ part,
                                               float* __restrict__ out)
{
    float s = 0.f;
    for (int i = threadIdx.x; i < 4096; i += 256) s += part[i];
    #pragma unroll
    for (int m = 1; m < 64; m <<= 1) s += __shfl_xor(s, m, 64);
    __shared__ float red[4];
    int w = threadIdx.x >> 6, lane = threadIdx.x & 63;
    if (lane == 0) red[w] = s;
    __syncthreads();
    if (threadIdx.x == 0)
        out[8388608] = (red[0] + red[1] + red[2] + red[3]) * (0.5f / 4194304.f);
}

// ---------------------------------------------------------------------------
extern "C" void kernel_launch(void* const* d_in, const int* in_sizes, int n_in,
                              void* d_out, int out_size, void* d_ws, size_t ws_size,
                              hipStream_t stream)
{
    (void)in_sizes; (void)n_in; (void)out_size; (void)ws_size;
    const float* dec   = (const float*)d_in[0];
    // d_in[1] = attn_mask: statically causal (j > i), not read
    const float* qm    = (const float*)d_in[2];
    const float* km    = (const float*)d_in[3];
    const float* vm    = (const float*)d_in[4];
    const float* qs    = (const float*)d_in[5];
    const float* ks    = (const float*)d_in[6];
    const float* vs    = (const float*)d_in[7];
    const float* om    = (const float*)d_in[8];
    const float* os    = (const float*)d_in[9];
    const float* gamma = (const float*)d_in[10];
    const float* beta  = (const float*)d_in[11];
    const float* eq    = (const float*)d_in[12];
    const float* ek    = (const float*)d_in[13];
    const float* ev    = (const float*)d_in[14];
    const float* eo    = (const float*)d_in[15];

    char* ws = (char*)d_ws;
    _Float16* WQ   = (_Float16*)ws;                       // 4 x 1M fp16 = 8 MB
    float*    PART = (float*)(ws + (8ull  << 20));        // 16 KB
    _Float16* XH   = (_Float16*)(ws + (9ull  << 20));     // 16 MB (later reused as Vt)
    _Float16* Qh   = (_Float16*)(ws + (25ull << 20));     // Q,K,V contiguous 48 MB
    _Float16* Kh   = Qh + 8388608;
    _Float16* Vh   = Qh + 16777216;
    _Float16* Vtg  = XH;                                  // XH dead after QKV GEMM
    _Float16* AV   = Vh;                                  // V dead after k_vtrans
    float*    out  = (float*)d_out;                       // x fp32 lives in d_out

    k_sample<<<dim3(4096), dim3(256), 0, stream>>>(
        qm, km, vm, qs, ks, vs, om, os, eq, ek, ev, eo,
        WQ, WQ + 1048576, WQ + 2097152, WQ + 3145728, PART);
    k_cvt<<<dim3(8192), dim3(256), 0, stream>>>(dec, XH);
    k_gemm<<<dim3(8, 64, 3), dim3(256), 0, stream>>>(XH, WQ, Qh, dec, out, 0);
    k_vtrans<<<dim3(128, 16), dim3(256), 0, stream>>>(Vh, Vtg);
    k_attn<<<dim3(128, 8), dim3(256), 0, stream>>>(Qh, Kh, Vtg, AV);
    k_gemm<<<dim3(8, 64, 1), dim3(256), 0, stream>>>(AV, WQ + 3145728, Qh, dec, out, 1);
    k_ln<<<dim3(8192), dim3(256), 0, stream>>>(out, gamma, beta);
    k_klfin<<<dim3(1), dim3(256), 0, stream>>>(PART, out);
}

// Round 3
// 355.391 us; speedup vs baseline: 1.2645x; 1.0317x over previous
//
#include <hip/hip_runtime.h>

typedef _Float16 f16x8 __attribute__((ext_vector_type(8)));
typedef _Float16 f16x4 __attribute__((ext_vector_type(4)));
typedef float    f32x4 __attribute__((ext_vector_type(4)));

static __device__ __forceinline__ f32x4 mfma16(f16x8 a, f16x8 b, f32x4 c) {
    return __builtin_amdgcn_mfma_f32_16x16x32_f16(a, b, c, 0, 0, 0);
}

// async global->LDS, 16B per lane; LDS dest is wave-uniform base + lane*16
static __device__ __forceinline__ void gload_lds16(const _Float16* g, _Float16* lds) {
    __builtin_amdgcn_global_load_lds(
        (const __attribute__((address_space(1))) unsigned int*)g,
        (__attribute__((address_space(3))) unsigned int*)lds, 16, 0, 0);
}

// ---------------------------------------------------------------------------
// Kernel 1: fused Bayesian weight sampling (+KL partials) and dec_inp cvt.
// blocks [0,4096): sample+KL.  blocks [4096,12288): fp32->fp16 convert.
// ---------------------------------------------------------------------------
__global__ __launch_bounds__(256) void k_prep(
    const float* __restrict__ qm, const float* __restrict__ km, const float* __restrict__ vm,
    const float* __restrict__ qs, const float* __restrict__ ks, const float* __restrict__ vs,
    const float* __restrict__ om, const float* __restrict__ os,
    const float* __restrict__ eq, const float* __restrict__ ek,
    const float* __restrict__ ev, const float* __restrict__ eo,
    _Float16* __restrict__ wq, _Float16* __restrict__ wk,
    _Float16* __restrict__ wv, _Float16* __restrict__ wo,
    float* __restrict__ part,
    const float* __restrict__ dec, _Float16* __restrict__ xh)
{
    if (blockIdx.x >= 4096) {
        int i = ((blockIdx.x - 4096) * 256 + threadIdx.x) * 4;
        float4 v = *(const float4*)&dec[i];
        f16x4 hv;
        hv[0] = (_Float16)v.x; hv[1] = (_Float16)v.y;
        hv[2] = (_Float16)v.z; hv[3] = (_Float16)v.w;
        *(f16x4*)&xh[i] = hv;
        return;
    }
    int i = blockIdx.x * 256 + threadIdx.x;
    float aqm = qm[i], akm = km[i], avm = vm[i];
    float aqs = qs[i], aks = ks[i], avs = vs[i];
    float aom = om[i], aos = os[i];
    wq[i] = (_Float16)(aqm + eq[i] * __expf(aqs));
    wk[i] = (_Float16)(akm + ek[i] * __expf(aks));
    wv[i] = (_Float16)(avm + ev[i] * __expf(avs));
    // faithful bug: output weight built from value_mean + eps_o*exp(output_std)
    wo[i] = (_Float16)(avm + eo[i] * __expf(aos));
    float t = aqm*aqm - 2.f*aqs + __expf(2.f*aqs)
            + akm*akm - 2.f*aks + __expf(2.f*aks)
            + avm*avm - 2.f*avs + __expf(2.f*avs)
            + aom*aom - 2.f*aos + __expf(2.f*aos);
    #pragma unroll
    for (int m = 1; m < 64; m <<= 1) t += __shfl_xor(t, m, 64);
    __shared__ float red[4];
    int w = threadIdx.x >> 6, lane = threadIdx.x & 63;
    if (lane == 0) red[w] = t;
    __syncthreads();
    if (threadIdx.x == 0) part[blockIdx.x] = red[0] + red[1] + red[2] + red[3];
}

// ---------------------------------------------------------------------------
// Kernel 2/5: C = A(M,K) * B(N,K)^T, 128x128 tile, BK=64, m97 structure.
// LDS k-chunks XOR-swizzled (chunk c of row r lives at pos c^(r&7)) so
// ds_read_b128 fans across all 32 banks (row stride 128B would otherwise
// put every row on the same 4 banks -> 2x read cost; measured 1.9e7 conflicts).
// mode 0: C fp16 (z==0 slice pre-scaled by 1/sqrt(Dh)); mode 1: xout=resid+C.
// ---------------------------------------------------------------------------
__global__ __launch_bounds__(256) void k_gemm(
    const _Float16* __restrict__ A, const _Float16* __restrict__ B0,
    _Float16* __restrict__ C0, const float* __restrict__ resid,
    float* __restrict__ xout, int mode)
{
    __shared__ __align__(16) _Float16 As[128 * 64];
    __shared__ __align__(16) _Float16 Bs[128 * 64];
    const int K = 1024, N = 1024;
    const _Float16* Bp = B0 + (size_t)blockIdx.z * 1048576u;
    _Float16* Cp = C0 + (size_t)blockIdx.z * 8388608u;
    int tN = blockIdx.x * 128, tM = blockIdx.y * 128;
    int tid = threadIdx.x, w = tid >> 6, lane = tid & 63;
    int wm = w & 1, wn = w >> 1;
    int q = lane >> 4, r = lane & 15;
    // staging: lane covers row = chunk*8 + (lane>>3), LDS pos c = lane&7;
    // fetch global chunk c ^ (row&7)  (row&7 == lane>>3 here)
    int csrc = ((lane & 7) ^ (lane >> 3)) * 8;
    int srow = lane >> 3;
    f32x4 acc[4][4] = {};
    for (int kk = 0; kk < K; kk += 64) {
        __syncthreads();            // prior ds_reads drained before restaging
        #pragma unroll
        for (int i = 0; i < 4; ++i) {
            int chunk = w * 4 + i;                 // 16 x 1KB chunks per matrix
            int row = chunk * 8 + srow;            // 0..127
            gload_lds16(A  + (size_t)(tM + row) * K + kk + csrc, &As[chunk * 512]);
            gload_lds16(Bp + (size_t)(tN + row) * K + kk + csrc, &Bs[chunk * 512]);
        }
        __syncthreads();            // vmcnt(0) drain lands the LDS data
        #pragma unroll
        for (int kc = 0; kc < 2; ++kc) {
            f16x8 af[4], bf[4];
            #pragma unroll
            for (int m = 0; m < 4; ++m) {
                int row = wm*64 + m*16 + r;
                int pos = ((kc*4 + q) ^ (r & 7)) * 8;
                af[m] = *(const f16x8*)&As[row*64 + pos];
            }
            #pragma unroll
            for (int n = 0; n < 4; ++n) {
                int row = wn*64 + n*16 + r;
                int pos = ((kc*4 + q) ^ (r & 7)) * 8;
                bf[n] = *(const f16x8*)&Bs[row*64 + pos];
            }
            #pragma unroll
            for (int m = 0; m < 4; ++m)
                #pragma unroll
                for (int n = 0; n < 4; ++n)
                    acc[m][n] = mfma16(af[m], bf[n], acc[m][n]);
        }
    }
    // softmax scale folded into Q (z==0) so attention hot loop has no scaling
    float sc = (mode == 0 && blockIdx.z == 0) ? 0.125f : 1.0f;
    // epilogue: C/D layout row = q*4+t, col = r  (verified m89/m91)
    #pragma unroll
    for (int m = 0; m < 4; ++m)
      #pragma unroll
      for (int n = 0; n < 4; ++n)
        #pragma unroll
        for (int t = 0; t < 4; ++t) {
            int row = tM + wm*64 + m*16 + q*4 + t;
            int col = tN + wn*64 + n*16 + r;
            size_t o = (size_t)row * N + col;
            if (mode == 0) Cp[o] = (_Float16)(acc[m][n][t] * sc);
            else           xout[o] = resid[o] + acc[m][n][t];
        }
}

// ---------------------------------------------------------------------------
// Kernel 3: transpose V once: [s][b][h*64+d] -> Vt[(b*16+h)*64+d][s]
// ---------------------------------------------------------------------------
__global__ __launch_bounds__(256) void k_vtrans(const _Float16* __restrict__ V,
                                                _Float16* __restrict__ Vt)
{
    __shared__ __align__(16) _Float16 L[64 * 72];
    int c = blockIdx.x;                 // b*16+h
    int b = c >> 4, h = c & 15;
    int s0 = blockIdx.y * 64;
    int tid = threadIdx.x;
    #pragma unroll
    for (int rep = 0; rep < 2; ++rep) {
        int idx = rep * 256 + tid;
        int sl = idx >> 3, ch = idx & 7;
        f16x8 v = *(const f16x8*)&V[((size_t)(s0 + sl) * 8 + b) * 1024 + h * 64 + ch * 8];
        *(f16x8*)&L[sl * 72 + ch * 8] = v;
    }
    __syncthreads();
    #pragma unroll
    for (int rep = 0; rep < 2; ++rep) {
        int idx = rep * 256 + tid;
        int d = idx >> 3, c2 = idx & 7;   // c2 fast -> coalesced 128B/8 lanes out
        f16x8 o;
        #pragma unroll
        for (int e = 0; e < 8; ++e) o[e] = L[(c2 * 8 + e) * 72 + d];
        *(f16x8*)&Vt[((size_t)c * 64 + d) * 1024 + s0 + c2 * 8] = o;
    }
}

// ---------------------------------------------------------------------------
// Kernel 4: causal flash attention, S^T formulation.
//   S^T = K·Q^T  -> lane holds j in registers (16/lane), i = lane r
//   softmax over j: in-register tree + 2 shuffles (xor 16/32)
//   O^T = V^T·P^T via mfma(A=V^T frag, B=P frag); P via vectorized LDS
// K/Vt tiles staged with the same XOR chunk swizzle as k_gemm.
// ---------------------------------------------------------------------------
__global__ __launch_bounds__(256, 4) void k_attn(
    const _Float16* __restrict__ Qb, const _Float16* __restrict__ Kb,
    const _Float16* __restrict__ Vtg, _Float16* __restrict__ AVo)
{
    __shared__ __align__(16) _Float16 Ks[64 * 64];   // rows j, cols d (swizzled)
    __shared__ __align__(16) _Float16 Vs[64 * 64];   // rows d, cols j (swizzled)
    __shared__ __align__(16) _Float16 Ps[4 * 32 * 72]; // per-wave P[i][j], pad 72
    const int bh = blockIdx.x;            // 0..127
    const int b = bh & 7, h = bh >> 3;
    const int cbh = b * 16 + h;           // Vt row-group index
    const int qt = blockIdx.y;            // 0..7
    const int tid = threadIdx.x, w = tid >> 6, lane = tid & 63;
    const int q = lane >> 4, r = lane & 15;
    const int i0 = qt * 128 + w * 32;     // this wave's i-base
    const int csrc = ((lane & 7) ^ (lane >> 3)) * 8;
    const int srow = lane >> 3;

    f16x8 qf[2][2];                       // Q B-fragments (pre-scaled by 0.125)
    #pragma unroll
    for (int it = 0; it < 2; ++it)
      #pragma unroll
      for (int kc = 0; kc < 2; ++kc)
        qf[it][kc] = *(const f16x8*)&Qb[((size_t)(i0 + it*16 + r)*8 + b)*1024 + h*64 + kc*32 + q*8];

    f32x4 ot[4][2] = {};                  // O^T acc: [dtb][it], d=dtb*16+q*4+t, i=it*16+r
    float mrun[2] = {-1e30f, -1e30f}, lrun[2] = {0.f, 0.f};
    _Float16* Pw = &Ps[w * 2304];

    auto tile = [&](int kt, bool MASK) __attribute__((always_inline)) {
        __syncthreads();                  // prior tile's LDS reads drained
        #pragma unroll
        for (int ii = 0; ii < 2; ++ii) {  // stage K-tile + Vt-tile, 8KB each
            int chunk = w * 2 + ii;
            int row = chunk * 8 + srow;
            gload_lds16(Kb  + ((size_t)(kt*64 + row)*8 + b)*1024 + h*64 + csrc, &Ks[chunk*512]);
            gload_lds16(Vtg + ((size_t)(cbh*64 + row))*1024 + kt*64 + csrc,     &Vs[chunk*512]);
        }
        __syncthreads();                  // vmcnt(0) drain lands the tiles

        f32x4 st[4][2] = {};              // S^T: [jt][it], j=jt*16+q*4+t, i=it*16+r
        #pragma unroll
        for (int kc = 0; kc < 2; ++kc) {
            f16x8 kf[4];
            #pragma unroll
            for (int jt = 0; jt < 4; ++jt) {
                int pos = ((kc*4 + q) ^ (r & 7)) * 8;
                kf[jt] = *(const f16x8*)&Ks[(jt*16 + r)*64 + pos];
            }
            #pragma unroll
            for (int jt = 0; jt < 4; ++jt)
              #pragma unroll
              for (int it = 0; it < 2; ++it)
                st[jt][it] = mfma16(kf[jt], qf[it][kc], st[jt][it]);
        }

        #pragma unroll
        for (int it = 0; it < 2; ++it) {
            if (MASK) {
                int il = i0 + it*16 + r;
                #pragma unroll
                for (int jt = 0; jt < 4; ++jt)
                  #pragma unroll
                  for (int t = 0; t < 4; ++t)
                    if (kt*64 + jt*16 + q*4 + t > il) st[jt][it][t] = -1e30f;
            }
            float mx = -1e30f;            // in-register max over 16 j values
            #pragma unroll
            for (int jt = 0; jt < 4; ++jt) {
                f32x4 s4 = st[jt][it];
                mx = fmaxf(mx, fmaxf(fmaxf(s4[0], s4[1]), fmaxf(s4[2], s4[3])));
            }
            mx = fmaxf(mx, __shfl_xor(mx, 16, 64));
            mx = fmaxf(mx, __shfl_xor(mx, 32, 64));
            float mnew = fmaxf(mrun[it], mx);
            float al = __expf(mrun[it] - mnew);
            mrun[it] = mnew;
            float ps = 0.f;
            #pragma unroll
            for (int jt = 0; jt < 4; ++jt) {   // exp + pack + vector LDS write
                f16x4 hv;
                #pragma unroll
                for (int t = 0; t < 4; ++t) {
                    float e = __expf(st[jt][it][t] - mnew);
                    ps += e;
                    hv[t] = (_Float16)e;
                }
                *(f16x4*)&Pw[(it*16 + r)*72 + jt*16 + q*4] = hv;
            }
            ps += __shfl_xor(ps, 16, 64);
            ps += __shfl_xor(ps, 32, 64);
            lrun[it] = lrun[it] * al + ps;
            #pragma unroll
            for (int dtb = 0; dtb < 4; ++dtb) ot[dtb][it] *= al;
        }

        #pragma unroll
        for (int kc = 0; kc < 2; ++kc) {  // O^T += V^T-frag x P-frag
            f16x8 vf[4], pf[2];
            #pragma unroll
            for (int dtb = 0; dtb < 4; ++dtb) {
                int pos = ((kc*4 + q) ^ (r & 7)) * 8;
                vf[dtb] = *(const f16x8*)&Vs[(dtb*16 + r)*64 + pos];
            }
            #pragma unroll
            for (int it = 0; it < 2; ++it)
                pf[it] = *(const f16x8*)&Pw[(it*16 + r)*72 + kc*32 + q*8];
            #pragma unroll
            for (int dtb = 0; dtb < 4; ++dtb)
              #pragma unroll
              for (int it = 0; it < 2; ++it)
                ot[dtb][it] = mfma16(vf[dtb], pf[it], ot[dtb][it]);
        }
    };

    for (int kt = 0; kt < 2*qt; ++kt) tile(kt, false);  // interior: no mask
    tile(2*qt,     true);                               // diagonal tiles
    tile(2*qt + 1, true);

    #pragma unroll
    for (int it = 0; it < 2; ++it) {
        float inv = 1.f / lrun[it];
        int s = i0 + it*16 + r;
        #pragma unroll
        for (int dtb = 0; dtb < 4; ++dtb) {
            f16x4 hv;
            #pragma unroll
            for (int t = 0; t < 4; ++t) hv[t] = (_Float16)(ot[dtb][it][t] * inv);
            *(f16x4*)&AVo[((size_t)s*8 + b)*1024 + h*64 + dtb*16 + q*4] = hv;
        }
    }
}

// ---------------------------------------------------------------------------
// Kernel 6: in-place LayerNorm on d_out rows (1024 wide); block 8192 = KL fin.
// ---------------------------------------------------------------------------
__global__ __launch_bounds__(256) void k_ln(float* __restrict__ x,
    const float* __restrict__ g, const float* __restrict__ bta,
    const float* __restrict__ part)
{
    __shared__ float rs[4], rs2[4];
    int w = threadIdx.x >> 6, lane = threadIdx.x & 63;
    if (blockIdx.x == 8192) {             // KL finalize
        float s = 0.f;
        for (int i = threadIdx.x; i < 4096; i += 256) s += part[i];
        #pragma unroll
        for (int m = 1; m < 64; m <<= 1) s += __shfl_xor(s, m, 64);
        if (lane == 0) rs[w] = s;
        __syncthreads();
        if (threadIdx.x == 0)
            x[8388608] = (rs[0] + rs[1] + rs[2] + rs[3]) * (0.5f / 4194304.f);
        return;
    }
    int row = blockIdx.x;
    float* xr = x + (size_t)row * 1024;
    int t4 = threadIdx.x * 4;
    float4 v = *(const float4*)&xr[t4];
    float s  = v.x + v.y + v.z + v.w;
    float s2 = v.x*v.x + v.y*v.y + v.z*v.z + v.w*v.w;
    #pragma unroll
    for (int m = 1; m < 64; m <<= 1) { s += __shfl_xor(s, m, 64); s2 += __shfl_xor(s2, m, 64); }
    if (lane == 0) { rs[w] = s; rs2[w] = s2; }
    __syncthreads();
    s  = rs[0] + rs[1] + rs[2] + rs[3];
    s2 = rs2[0] + rs2[1] + rs2[2] + rs2[3];
    float mu = s * (1.f / 1024.f);
    float var = s2 * (1.f / 1024.f) - mu * mu;
    float rstd = rsqrtf(var + 1e-5f);
    float4 gv = *(const float4*)&g[t4];
    float4 bv = *(const float4*)&bta[t4];
    float4 ov;
    ov.x = (v.x - mu) * rstd * gv.x + bv.x;
    ov.y = (v.y - mu) * rstd * gv.y + bv.y;
    ov.z = (v.z - mu) * rstd * gv.z + bv.z;
    ov.w = (v.w - mu) * rstd * gv.w + bv.w;
    *(float4*)&xr[t4] = ov;
}

// ---------------------------------------------------------------------------
extern "C" void kernel_launch(void* const* d_in, const int* in_sizes, int n_in,
                              void* d_out, int out_size, void* d_ws, size_t ws_size,
                              hipStream_t stream)
{
    (void)in_sizes; (void)n_in; (void)out_size; (void)ws_size;
    const float* dec   = (const float*)d_in[0];
    // d_in[1] = attn_mask: statically causal (j > i), not read
    const float* qm    = (const float*)d_in[2];
    const float* km    = (const float*)d_in[3];
    const float* vm    = (const float*)d_in[4];
    const float* qs    = (const float*)d_in[5];
    const float* ks    = (const float*)d_in[6];
    const float* vs    = (const float*)d_in[7];
    const float* om    = (const float*)d_in[8];
    const float* os    = (const float*)d_in[9];
    const float* gamma = (const float*)d_in[10];
    const float* beta  = (const float*)d_in[11];
    const float* eq    = (const float*)d_in[12];
    const float* ek    = (const float*)d_in[13];
    const float* ev    = (const float*)d_in[14];
    const float* eo    = (const float*)d_in[15];

    char* ws = (char*)d_ws;
    _Float16* WQ   = (_Float16*)ws;                       // 4 x 1M fp16 = 8 MB
    float*    PART = (float*)(ws + (8ull  << 20));        // 16 KB
    _Float16* XH   = (_Float16*)(ws + (9ull  << 20));     // 16 MB (later reused as Vt)
    _Float16* Qh   = (_Float16*)(ws + (25ull << 20));     // Q,K,V contiguous 48 MB
    _Float16* Kh   = Qh + 8388608;
    _Float16* Vh   = Qh + 16777216;
    _Float16* Vtg  = XH;                                  // XH dead after QKV GEMM
    _Float16* AV   = Vh;                                  // V dead after k_vtrans
    float*    out  = (float*)d_out;                       // x fp32 lives in d_out

    k_prep<<<dim3(12288), dim3(256), 0, stream>>>(
        qm, km, vm, qs, ks, vs, om, os, eq, ek, ev, eo,
        WQ, WQ + 1048576, WQ + 2097152, WQ + 3145728, PART, dec, XH);
    k_gemm<<<dim3(8, 64, 3), dim3(256), 0, stream>>>(XH, WQ, Qh, dec, out, 0);
    k_vtrans<<<dim3(128, 16), dim3(256), 0, stream>>>(Vh, Vtg);
    k_attn<<<dim3(128, 8), dim3(256), 0, stream>>>(Qh, Kh, Vtg, AV);
    k_gemm<<<dim3(8, 64, 1), dim3(256), 0, stream>>>(AV, WQ + 3145728, Qh, dec, out, 1);
    k_ln<<<dim3(8193), dim3(256), 0, stream>>>(out, gamma, beta, PART);
}

// Round 4
// 339.430 us; speedup vs baseline: 1.3240x; 1.0470x over previous
//
#include <hip/hip_runtime.h>

typedef _Float16 f16x8 __attribute__((ext_vector_type(8)));
typedef _Float16 f16x4 __attribute__((ext_vector_type(4)));
typedef float    f32x4 __attribute__((ext_vector_type(4)));

static __device__ __forceinline__ f32x4 mfma16(f16x8 a, f16x8 b, f32x4 c) {
    return __builtin_amdgcn_mfma_f32_16x16x32_f16(a, b, c, 0, 0, 0);
}

// async global->LDS, 16B per lane; LDS dest is wave-uniform base + lane*16
static __device__ __forceinline__ void gload_lds16(const _Float16* g, _Float16* lds) {
    __builtin_amdgcn_global_load_lds(
        (const __attribute__((address_space(1))) unsigned int*)g,
        (__attribute__((address_space(3))) unsigned int*)lds, 16, 0, 0);
}

// ---------------------------------------------------------------------------
// Kernel 1: fused Bayesian weight sampling (+KL partials) and dec_inp cvt.
// blocks [0,4096): sample+KL.  blocks [4096,12288): fp32->fp16 convert.
// ---------------------------------------------------------------------------
__global__ __launch_bounds__(256) void k_prep(
    const float* __restrict__ qm, const float* __restrict__ km, const float* __restrict__ vm,
    const float* __restrict__ qs, const float* __restrict__ ks, const float* __restrict__ vs,
    const float* __restrict__ om, const float* __restrict__ os,
    const float* __restrict__ eq, const float* __restrict__ ek,
    const float* __restrict__ ev, const float* __restrict__ eo,
    _Float16* __restrict__ wq, _Float16* __restrict__ wk,
    _Float16* __restrict__ wv, _Float16* __restrict__ wo,
    float* __restrict__ part,
    const float* __restrict__ dec, _Float16* __restrict__ xh)
{
    if (blockIdx.x >= 4096) {
        int i = ((blockIdx.x - 4096) * 256 + threadIdx.x) * 4;
        float4 v = *(const float4*)&dec[i];
        f16x4 hv;
        hv[0] = (_Float16)v.x; hv[1] = (_Float16)v.y;
        hv[2] = (_Float16)v.z; hv[3] = (_Float16)v.w;
        *(f16x4*)&xh[i] = hv;
        return;
    }
    int i = blockIdx.x * 256 + threadIdx.x;
    float aqm = qm[i], akm = km[i], avm = vm[i];
    float aqs = qs[i], aks = ks[i], avs = vs[i];
    float aom = om[i], aos = os[i];
    wq[i] = (_Float16)(aqm + eq[i] * __expf(aqs));
    wk[i] = (_Float16)(akm + ek[i] * __expf(aks));
    wv[i] = (_Float16)(avm + ev[i] * __expf(avs));
    // faithful bug: output weight built from value_mean + eps_o*exp(output_std)
    wo[i] = (_Float16)(avm + eo[i] * __expf(aos));
    float t = aqm*aqm - 2.f*aqs + __expf(2.f*aqs)
            + akm*akm - 2.f*aks + __expf(2.f*aks)
            + avm*avm - 2.f*avs + __expf(2.f*avs)
            + aom*aom - 2.f*aos + __expf(2.f*aos);
    #pragma unroll
    for (int m = 1; m < 64; m <<= 1) t += __shfl_xor(t, m, 64);
    __shared__ float red[4];
    int w = threadIdx.x >> 6, lane = threadIdx.x & 63;
    if (lane == 0) red[w] = t;
    __syncthreads();
    if (threadIdx.x == 0) part[blockIdx.x] = red[0] + red[1] + red[2] + red[3];
}

// ---------------------------------------------------------------------------
// Kernel 2/5: C = A(M,K) * B(N,K)^T, 128x128 tile, BK=64, m97 structure.
// LDS k-chunks XOR-swizzled (chunk c of row r lives at pos c^(r&7)):
// row stride 128B = 32 banks would put every row's chunk on the same 4 banks
// (measured 1.9e7 conflicts -> 0 after swizzle).
// Block remap: xcd = flat&7 owns M-tile group xcd*8..+8 for ALL N-tiles, so
// one XCD's ~64 co-resident blocks share a 2MB A-slice + 2MB B-slice = its
// 4MB L2 (blocks dispatch round-robin over 8 XCDs). Without this, the 8
// N-tiles of an M-row land on 8 different XCDs -> every XCD refetches all
// of A from HBM (measured 200MB fetch vs 22MB unique).
// mode 0: C fp16 (z==0 slice pre-scaled by 1/sqrt(Dh)); mode 1: xout=resid+C.
// ---------------------------------------------------------------------------
__global__ __launch_bounds__(256) void k_gemm(
    const _Float16* __restrict__ A, const _Float16* __restrict__ B0,
    _Float16* __restrict__ C0, const float* __restrict__ resid,
    float* __restrict__ xout, int mode)
{
    __shared__ __align__(16) _Float16 As[128 * 64];
    __shared__ __align__(16) _Float16 Bs[128 * 64];
    const int K = 1024, N = 1024;
    const _Float16* Bp = B0 + (size_t)blockIdx.z * 1048576u;
    _Float16* Cp = C0 + (size_t)blockIdx.z * 8388608u;
    int flat = blockIdx.y * 8 + blockIdx.x;        // 0..511
    int xcd = flat & 7, j = flat >> 3;
    int tM = (xcd * 8 + (j & 7)) * 128;            // M-group per XCD
    int tN = (j >> 3) * 128;
    int tid = threadIdx.x, w = tid >> 6, lane = tid & 63;
    int wm = w & 1, wn = w >> 1;
    int q = lane >> 4, r = lane & 15;
    // staging: lane covers row = chunk*8 + (lane>>3), LDS pos c = lane&7;
    // fetch global chunk c ^ (row&7)  (row&7 == lane>>3 here)
    int csrc = ((lane & 7) ^ (lane >> 3)) * 8;
    int srow = lane >> 3;
    f32x4 acc[4][4] = {};
    for (int kk = 0; kk < K; kk += 64) {
        __syncthreads();            // prior ds_reads drained before restaging
        #pragma unroll
        for (int i = 0; i < 4; ++i) {
            int chunk = w * 4 + i;                 // 16 x 1KB chunks per matrix
            int row = chunk * 8 + srow;            // 0..127
            gload_lds16(A  + (size_t)(tM + row) * K + kk + csrc, &As[chunk * 512]);
            gload_lds16(Bp + (size_t)(tN + row) * K + kk + csrc, &Bs[chunk * 512]);
        }
        __syncthreads();            // vmcnt(0) drain lands the LDS data
        #pragma unroll
        for (int kc = 0; kc < 2; ++kc) {
            f16x8 af[4], bf[4];
            #pragma unroll
            for (int m = 0; m < 4; ++m) {
                int row = wm*64 + m*16 + r;
                int pos = ((kc*4 + q) ^ (r & 7)) * 8;
                af[m] = *(const f16x8*)&As[row*64 + pos];
            }
            #pragma unroll
            for (int n = 0; n < 4; ++n) {
                int row = wn*64 + n*16 + r;
                int pos = ((kc*4 + q) ^ (r & 7)) * 8;
                bf[n] = *(const f16x8*)&Bs[row*64 + pos];
            }
            #pragma unroll
            for (int m = 0; m < 4; ++m)
                #pragma unroll
                for (int n = 0; n < 4; ++n)
                    acc[m][n] = mfma16(af[m], bf[n], acc[m][n]);
        }
    }
    // softmax scale folded into Q (z==0) so attention hot loop has no scaling
    float sc = (mode == 0 && blockIdx.z == 0) ? 0.125f : 1.0f;
    // epilogue: C/D layout row = q*4+t, col = r  (verified m89/m91)
    #pragma unroll
    for (int m = 0; m < 4; ++m)
      #pragma unroll
      for (int n = 0; n < 4; ++n)
        #pragma unroll
        for (int t = 0; t < 4; ++t) {
            int row = tM + wm*64 + m*16 + q*4 + t;
            int col = tN + wn*64 + n*16 + r;
            size_t o = (size_t)row * N + col;
            if (mode == 0) Cp[o] = (_Float16)(acc[m][n][t] * sc);
            else           xout[o] = resid[o] + acc[m][n][t];
        }
}

// ---------------------------------------------------------------------------
// Kernel 3: transpose V once: [s][b][h*64+d] -> Vt[(b*16+h)*64+d][s]
// ---------------------------------------------------------------------------
__global__ __launch_bounds__(256) void k_vtrans(const _Float16* __restrict__ V,
                                                _Float16* __restrict__ Vt)
{
    __shared__ __align__(16) _Float16 L[64 * 72];
    int c = blockIdx.x;                 // b*16+h
    int b = c >> 4, h = c & 15;
    int s0 = blockIdx.y * 64;
    int tid = threadIdx.x;
    #pragma unroll
    for (int rep = 0; rep < 2; ++rep) {
        int idx = rep * 256 + tid;
        int sl = idx >> 3, ch = idx & 7;
        f16x8 v = *(const f16x8*)&V[((size_t)(s0 + sl) * 8 + b) * 1024 + h * 64 + ch * 8];
        *(f16x8*)&L[sl * 72 + ch * 8] = v;
    }
    __syncthreads();
    #pragma unroll
    for (int rep = 0; rep < 2; ++rep) {
        int idx = rep * 256 + tid;
        int d = idx >> 3, c2 = idx & 7;   // c2 fast -> coalesced 128B/8 lanes out
        f16x8 o;
        #pragma unroll
        for (int e = 0; e < 8; ++e) o[e] = L[(c2 * 8 + e) * 72 + d];
        *(f16x8*)&Vt[((size_t)c * 64 + d) * 1024 + s0 + c2 * 8] = o;
    }
}

// ---------------------------------------------------------------------------
// Kernel 4: causal flash attention, S^T formulation.
//   S^T = K·Q^T  -> lane holds j in registers (16/lane), i = lane r
//   softmax over j: in-register tree + 2 shuffles (xor 16/32)
//   O^T = V^T·P^T via mfma(A=V^T frag, B=P frag); P via vectorized LDS
// K/Vt tiles staged with the same XOR chunk swizzle as k_gemm.
// grid (bh,qt): flat%8 == bh%8 for all qt -> each bh's K/V naturally stays
// on one XCD's L2 (no remap needed).
// ---------------------------------------------------------------------------
__global__ __launch_bounds__(256, 4) void k_attn(
    const _Float16* __restrict__ Qb, const _Float16* __restrict__ Kb,
    const _Float16* __restrict__ Vtg, _Float16* __restrict__ AVo)
{
    __shared__ __align__(16) _Float16 Ks[64 * 64];   // rows j, cols d (swizzled)
    __shared__ __align__(16) _Float16 Vs[64 * 64];   // rows d, cols j (swizzled)
    __shared__ __align__(16) _Float16 Ps[4 * 32 * 72]; // per-wave P[i][j], pad 72
    const int bh = blockIdx.x;            // 0..127
    const int b = bh & 7, h = bh >> 3;
    const int cbh = b * 16 + h;           // Vt row-group index
    const int qt = blockIdx.y;            // 0..7
    const int tid = threadIdx.x, w = tid >> 6, lane = tid & 63;
    const int q = lane >> 4, r = lane & 15;
    const int i0 = qt * 128 + w * 32;     // this wave's i-base
    const int csrc = ((lane & 7) ^ (lane >> 3)) * 8;
    const int srow = lane >> 3;

    f16x8 qf[2][2];                       // Q B-fragments (pre-scaled by 0.125)
    #pragma unroll
    for (int it = 0; it < 2; ++it)
      #pragma unroll
      for (int kc = 0; kc < 2; ++kc)
        qf[it][kc] = *(const f16x8*)&Qb[((size_t)(i0 + it*16 + r)*8 + b)*1024 + h*64 + kc*32 + q*8];

    f32x4 ot[4][2] = {};                  // O^T acc: [dtb][it], d=dtb*16+q*4+t, i=it*16+r
    float mrun[2] = {-1e30f, -1e30f}, lrun[2] = {0.f, 0.f};
    _Float16* Pw = &Ps[w * 2304];

    auto tile = [&](int kt, bool MASK) __attribute__((always_inline)) {
        __syncthreads();                  // prior tile's LDS reads drained
        #pragma unroll
        for (int ii = 0; ii < 2; ++ii) {  // stage K-tile + Vt-tile, 8KB each
            int chunk = w * 2 + ii;
            int row = chunk * 8 + srow;
            gload_lds16(Kb  + ((size_t)(kt*64 + row)*8 + b)*1024 + h*64 + csrc, &Ks[chunk*512]);
            gload_lds16(Vtg + ((size_t)(cbh*64 + row))*1024 + kt*64 + csrc,     &Vs[chunk*512]);
        }
        __syncthreads();                  // vmcnt(0) drain lands the tiles

        f32x4 st[4][2] = {};              // S^T: [jt][it], j=jt*16+q*4+t, i=it*16+r
        #pragma unroll
        for (int kc = 0; kc < 2; ++kc) {
            f16x8 kf[4];
            #pragma unroll
            for (int jt = 0; jt < 4; ++jt) {
                int pos = ((kc*4 + q) ^ (r & 7)) * 8;
                kf[jt] = *(const f16x8*)&Ks[(jt*16 + r)*64 + pos];
            }
            #pragma unroll
            for (int jt = 0; jt < 4; ++jt)
              #pragma unroll
              for (int it = 0; it < 2; ++it)
                st[jt][it] = mfma16(kf[jt], qf[it][kc], st[jt][it]);
        }

        #pragma unroll
        for (int it = 0; it < 2; ++it) {
            if (MASK) {
                int il = i0 + it*16 + r;
                #pragma unroll
                for (int jt = 0; jt < 4; ++jt)
                  #pragma unroll
                  for (int t = 0; t < 4; ++t)
                    if (kt*64 + jt*16 + q*4 + t > il) st[jt][it][t] = -1e30f;
            }
            float mx = -1e30f;            // in-register max over 16 j values
            #pragma unroll
            for (int jt = 0; jt < 4; ++jt) {
                f32x4 s4 = st[jt][it];
                mx = fmaxf(mx, fmaxf(fmaxf(s4[0], s4[1]), fmaxf(s4[2], s4[3])));
            }
            mx = fmaxf(mx, __shfl_xor(mx, 16, 64));
            mx = fmaxf(mx, __shfl_xor(mx, 32, 64));
            float mnew = fmaxf(mrun[it], mx);
            float al = __expf(mrun[it] - mnew);
            mrun[it] = mnew;
            float ps = 0.f;
            #pragma unroll
            for (int jt = 0; jt < 4; ++jt) {   // exp + pack + vector LDS write
                f16x4 hv;
                #pragma unroll
                for (int t = 0; t < 4; ++t) {
                    float e = __expf(st[jt][it][t] - mnew);
                    ps += e;
                    hv[t] = (_Float16)e;
                }
                *(f16x4*)&Pw[(it*16 + r)*72 + jt*16 + q*4] = hv;
            }
            ps += __shfl_xor(ps, 16, 64);
            ps += __shfl_xor(ps, 32, 64);
            lrun[it] = lrun[it] * al + ps;
            #pragma unroll
            for (int dtb = 0; dtb < 4; ++dtb) ot[dtb][it] *= al;
        }

        #pragma unroll
        for (int kc = 0; kc < 2; ++kc) {  // O^T += V^T-frag x P-frag
            f16x8 vf[4], pf[2];
            #pragma unroll
            for (int dtb = 0; dtb < 4; ++dtb) {
                int pos = ((kc*4 + q) ^ (r & 7)) * 8;
                vf[dtb] = *(const f16x8*)&Vs[(dtb*16 + r)*64 + pos];
            }
            #pragma unroll
            for (int it = 0; it < 2; ++it)
                pf[it] = *(const f16x8*)&Pw[(it*16 + r)*72 + kc*32 + q*8];
            #pragma unroll
            for (int dtb = 0; dtb < 4; ++dtb)
              #pragma unroll
              for (int it = 0; it < 2; ++it)
                ot[dtb][it] = mfma16(vf[dtb], pf[it], ot[dtb][it]);
        }
    };

    for (int kt = 0; kt < 2*qt; ++kt) tile(kt, false);  // interior: no mask
    tile(2*qt,     true);                               // diagonal tiles
    tile(2*qt + 1, true);

    #pragma unroll
    for (int it = 0; it < 2; ++it) {
        float inv = 1.f / lrun[it];
        int s = i0 + it*16 + r;
        #pragma unroll
        for (int dtb = 0; dtb < 4; ++dtb) {
            f16x4 hv;
            #pragma unroll
            for (int t = 0; t < 4; ++t) hv[t] = (_Float16)(ot[dtb][it][t] * inv);
            *(f16x4*)&AVo[((size_t)s*8 + b)*1024 + h*64 + dtb*16 + q*4] = hv;
        }
    }
}

// ---------------------------------------------------------------------------
// Kernel 6: in-place LayerNorm on d_out rows (1024 wide); block 8192 = KL fin.
// ---------------------------------------------------------------------------
__global__ __launch_bounds__(256) void k_ln(float* __restrict__ x,
    const float* __restrict__ g, const float* __restrict__ bta,
    const float* __restrict__ part)
{
    __shared__ float rs[4], rs2[4];
    int w = threadIdx.x >> 6, lane = threadIdx.x & 63;
    if (blockIdx.x == 8192) {             // KL finalize
        float s = 0.f;
        for (int i = threadIdx.x; i < 4096; i += 256) s += part[i];
        #pragma unroll
        for (int m = 1; m < 64; m <<= 1) s += __shfl_xor(s, m, 64);
        if (lane == 0) rs[w] = s;
        __syncthreads();
        if (threadIdx.x == 0)
            x[8388608] = (rs[0] + rs[1] + rs[2] + rs[3]) * (0.5f / 4194304.f);
        return;
    }
    int row = blockIdx.x;
    float* xr = x + (size_t)row * 1024;
    int t4 = threadIdx.x * 4;
    float4 v = *(const float4*)&xr[t4];
    float s  = v.x + v.y + v.z + v.w;
    float s2 = v.x*v.x + v.y*v.y + v.z*v.z + v.w*v.w;
    #pragma unroll
    for (int m = 1; m < 64; m <<= 1) { s += __shfl_xor(s, m, 64); s2 += __shfl_xor(s2, m, 64); }
    if (lane == 0) { rs[w] = s; rs2[w] = s2; }
    __syncthreads();
    s  = rs[0] + rs[1] + rs[2] + rs[3];
    s2 = rs2[0] + rs2[1] + rs2[2] + rs2[3];
    float mu = s * (1.f / 1024.f);
    float var = s2 * (1.f / 1024.f) - mu * mu;
    float rstd = rsqrtf(var + 1e-5f);
    float4 gv = *(const float4*)&g[t4];
    float4 bv = *(const float4*)&bta[t4];
    float4 ov;
    ov.x = (v.x - mu) * rstd * gv.x + bv.x;
    ov.y = (v.y - mu) * rstd * gv.y + bv.y;
    ov.z = (v.z - mu) * rstd * gv.z + bv.z;
    ov.w = (v.w - mu) * rstd * gv.w + bv.w;
    *(float4*)&xr[t4] = ov;
}

// ---------------------------------------------------------------------------
extern "C" void kernel_launch(void* const* d_in, const int* in_sizes, int n_in,
                              void* d_out, int out_size, void* d_ws, size_t ws_size,
                              hipStream_t stream)
{
    (void)in_sizes; (void)n_in; (void)out_size; (void)ws_size;
    const float* dec   = (const float*)d_in[0];
    // d_in[1] = attn_mask: statically causal (j > i), not read
    const float* qm    = (const float*)d_in[2];
    const float* km    = (const float*)d_in[3];
    const float* vm    = (const float*)d_in[4];
    const float* qs    = (const float*)d_in[5];
    const float* ks    = (const float*)d_in[6];
    const float* vs    = (const float*)d_in[7];
    const float* om    = (const float*)d_in[8];
    const float* os    = (const float*)d_in[9];
    const float* gamma = (const float*)d_in[10];
    const float* beta  = (const float*)d_in[11];
    const float* eq    = (const float*)d_in[12];
    const float* ek    = (const float*)d_in[13];
    const float* ev    = (const float*)d_in[14];
    const float* eo    = (const float*)d_in[15];

    char* ws = (char*)d_ws;
    _Float16* WQ   = (_Float16*)ws;                       // 4 x 1M fp16 = 8 MB
    float*    PART = (float*)(ws + (8ull  << 20));        // 16 KB
    _Float16* XH   = (_Float16*)(ws + (9ull  << 20));     // 16 MB (later reused as Vt)
    _Float16* Qh   = (_Float16*)(ws + (25ull << 20));     // Q,K,V contiguous 48 MB
    _Float16* Kh   = Qh + 8388608;
    _Float16* Vh   = Qh + 16777216;
    _Float16* Vtg  = XH;                                  // XH dead after QKV GEMM
    _Float16* AV   = Vh;                                  // V dead after k_vtrans
    float*    out  = (float*)d_out;                       // x fp32 lives in d_out

    k_prep<<<dim3(12288), dim3(256), 0, stream>>>(
        qm, km, vm, qs, ks, vs, om, os, eq, ek, ev, eo,
        WQ, WQ + 1048576, WQ + 2097152, WQ + 3145728, PART, dec, XH);
    k_gemm<<<dim3(8, 64, 3), dim3(256), 0, stream>>>(XH, WQ, Qh, dec, out, 0);
    k_vtrans<<<dim3(128, 16), dim3(256), 0, stream>>>(Vh, Vtg);
    k_attn<<<dim3(128, 8), dim3(256), 0, stream>>>(Qh, Kh, Vtg, AV);
    k_gemm<<<dim3(8, 64, 1), dim3(256), 0, stream>>>(AV, WQ + 3145728, Qh, dec, out, 1);
    k_ln<<<dim3(8193), dim3(256), 0, stream>>>(out, gamma, beta, PART);
}